// Round 1
// baseline (46027.817 us; speedup 1.0000x reference)
//
#include <hip/hip_runtime.h>
#include <cmath>

// ---------------- problem constants ----------------
#define BATCH 64
#define SEQL  512
#define INDIM 512
#define HID   768
#define G4    3072          // 4*HID
#define KTOT  1280          // INDIM + HID
#define KS    10            // K splits (K chunk = 128)
#define KC    128
#define JB    12            // row blocks of 256 rows
#define RPB   256
#define NBLK  240           // 2 dirs * JB * KS
#define NTHR  256
#define E2    (2*BATCH*HID)            // 98304 state elements
#define HALLN ((size_t)BATCH*SEQL*2*HID) // 50331648 floats of h_all

// ---------------- device-scope grid barrier (monotonic counter) ----------------
__device__ __forceinline__ void grid_barrier(unsigned* cnt, unsigned target) {
    __syncthreads();
    if (threadIdx.x == 0) {
        __threadfence();  // make prior writes device-visible
        __hip_atomic_fetch_add(cnt, 1u, __ATOMIC_RELAXED, __HIP_MEMORY_SCOPE_AGENT);
        while (__hip_atomic_load(cnt, __ATOMIC_RELAXED, __HIP_MEMORY_SCOPE_AGENT) < target)
            __builtin_amdgcn_s_sleep(1);
        __threadfence();  // invalidate caches before consuming others' writes
    }
    __syncthreads();
}

__device__ __forceinline__ float sigmoidf_(float x) { return 1.0f / (1.0f + expf(-x)); }

// ---------------- pre-kernel: transpose x -> xT[t][k][b] ----------------
__global__ __launch_bounds__(256) void k_transpose_x(const float* __restrict__ x,
                                                     float* __restrict__ xT) {
    __shared__ float tile[64][65];
    const int bidx = blockIdx.x;         // 512 * 8
    const int t  = bidx >> 3;
    const int kt = (bidx & 7) * 64;
    const int tid = threadIdx.x;
#pragma unroll
    for (int p = 0; p < 16; ++p) {
        int idx = p * 256 + tid;         // 0..4095
        int b = idx >> 6, kl = idx & 63;
        tile[b][kl] = x[((size_t)b * SEQL + t) * INDIM + kt + kl];
    }
    __syncthreads();
#pragma unroll
    for (int p = 0; p < 16; ++p) {
        int idx = p * 256 + tid;
        int kl = idx >> 6, b = idx & 63;
        xT[((size_t)t * INDIM + kt + kl) * BATCH + b] = tile[b][kl];
    }
}

// ---------------- pre-kernel: pack weights -> Wt[d][k][r] (k = [ih | hh]) ----------------
__global__ __launch_bounds__(256) void k_pack_w(const float* __restrict__ wih0,
                                                const float* __restrict__ whh0,
                                                const float* __restrict__ wih1,
                                                const float* __restrict__ whh1,
                                                float* __restrict__ Wt) {
    __shared__ float tile[64][65];
    const int bidx = blockIdx.x;         // 2 * 20 * 48
    const int d   = bidx / 960;
    const int rem = bidx % 960;
    const int kt  = rem / 48;            // 0..19
    const int rt  = rem % 48;            // 0..47
    const float* wih = d ? wih1 : wih0;
    const float* whh = d ? whh1 : whh0;
    const int kbase = kt * 64, rbase = rt * 64;
    const int tid = threadIdx.x;
#pragma unroll
    for (int p = 0; p < 16; ++p) {
        int idx = p * 256 + tid;
        int rl = idx >> 6, kl = idx & 63;
        int k = kbase + kl, r = rbase + rl;
        float v = (k < INDIM) ? wih[(size_t)r * INDIM + k]
                              : whh[(size_t)r * HID + (k - INDIM)];
        tile[rl][kl] = v;
    }
    __syncthreads();
#pragma unroll
    for (int p = 0; p < 16; ++p) {
        int idx = p * 256 + tid;
        int kl = idx >> 6, rl = idx & 63;
        Wt[((size_t)d * KTOT + kbase + kl) * G4 + rbase + rl] = tile[rl][kl];
    }
}

// ---------------- persistent bidirectional LSTM kernel ----------------
// blocks: bid -> d (dir), rb (row block of 256 gate-rows), kb (K chunk of 128)
// per step: phase1 partial GEMM -> Gpart ; barrier ; phase2 reduce+activations+state ; barrier
__global__ __launch_bounds__(NTHR, 2)
void k_lstm_persist(const float* __restrict__ x,   const float* __restrict__ xT, int use_xt,
                    const float* __restrict__ Wt,  int use_wt,
                    const float* __restrict__ wih0, const float* __restrict__ whh0,
                    const float* __restrict__ wih1, const float* __restrict__ whh1,
                    const float* __restrict__ bias0, const float* __restrict__ bias1,
                    const float* __restrict__ h0,   const float* __restrict__ c0,
                    float* __restrict__ out,  float* __restrict__ Gpart,
                    float* __restrict__ hT,   float* __restrict__ cbuf,
                    unsigned* __restrict__ barcnt)
{
    __shared__ float InL[32][64];     // [k][b]      8 KB
    __shared__ float WL[32][256];     // [k][r]     32 KB
    const int tid = threadIdx.x;
    const int bid = blockIdx.x;
    const int d   = bid / (JB * KS);
    const int rem = bid % (JB * KS);
    const int rb  = rem / KS;
    const int kb  = rem % KS;
    const int r0  = rb * RPB;
    const int k0  = kb * KC;
    const int tr  = tid & 31;         // 32 r-threads
    const int tb  = tid >> 5;         // 8 b-threads
    const int gtid = bid * NTHR + tid;
    unsigned bar = 0;

    // ---- init: h0 -> hT (transposed), c0 -> cbuf ----
    for (int e = gtid; e < E2; e += NBLK * NTHR) {
        int b = e / (2 * HID); int rr = e % (2 * HID); int dd = rr / HID; int j = rr % HID;
        size_t src = (size_t)(dd * BATCH + b) * HID + j;
        hT[(size_t)(dd * HID + j) * BATCH + b] = h0[src];
        cbuf[src] = c0[src];
    }
    grid_barrier(barcnt, (++bar) * NBLK);

    for (int t = 0; t < SEQL; ++t) {
        const int t_eff = d ? (SEQL - 1 - t) : t;

        // ================= phase 1: partial GEMM =================
        float acc[8][8];
#pragma unroll
        for (int i = 0; i < 8; ++i)
#pragma unroll
            for (int m = 0; m < 8; ++m) acc[i][m] = 0.0f;

        for (int kc = 0; kc < KC; kc += 32) {
            __syncthreads();
            // ---- stage In (32 k x 64 b) ----
            if (k0 >= INDIM || use_xt) {
                // vectorized: both xT and hT are [row][b] with b contiguous
#pragma unroll
                for (int p = 0; p < 2; ++p) {
                    int idx = p * NTHR + tid;          // 0..511
                    int b4 = idx & 15, kr = idx >> 4;  // kr 0..31
                    int k = k0 + kc + kr;
                    const float* src = (k < INDIM)
                        ? (xT + ((size_t)t_eff * INDIM + k) * BATCH)
                        : (hT + ((size_t)d * HID + (k - INDIM)) * BATCH);
                    *(float4*)&InL[kr][b4 * 4] = *(const float4*)(src + b4 * 4);
                }
            } else {
                // fallback: read x directly (strided)
#pragma unroll
                for (int p = 0; p < 8; ++p) {
                    int idx = p * NTHR + tid;
                    int b = idx & 63, kr = idx >> 6;
                    int k = k0 + kc + kr;
                    InL[kr][b] = x[((size_t)b * SEQL + t_eff) * INDIM + k];
                }
            }
            // ---- stage W (32 k x 256 r) ----
            if (use_wt) {
                const float* wbase = Wt + (size_t)d * KTOT * G4;
#pragma unroll
                for (int p = 0; p < 8; ++p) {
                    int idx = p * NTHR + tid;
                    int f4 = idx & 63, kr = idx >> 6;
                    int k = k0 + kc + kr;
                    *(float4*)&WL[kr][f4 * 4] =
                        *(const float4*)(wbase + (size_t)k * G4 + r0 + f4 * 4);
                }
            } else {
                const float* wih = d ? wih1 : wih0;
                const float* whh = d ? whh1 : whh0;
#pragma unroll
                for (int p = 0; p < 8; ++p) {
                    int idx = p * NTHR + tid;
                    int f4 = idx & 63, kr = idx >> 6;
                    int k = k0 + kc + kr;
#pragma unroll
                    for (int m = 0; m < 4; ++m) {
                        int r = r0 + f4 * 4 + m;
                        WL[kr][f4 * 4 + m] = (k < INDIM)
                            ? wih[(size_t)r * INDIM + k]
                            : whh[(size_t)r * HID + (k - INDIM)];
                    }
                }
            }
            __syncthreads();
            // ---- 32 k-iters, 64 FMA each ----
#pragma unroll 4
            for (int k = 0; k < 32; ++k) {
                float4 a0 = *(const float4*)&InL[k][tb * 8];
                float4 a1 = *(const float4*)&InL[k][tb * 8 + 4];
                float4 w0 = *(const float4*)&WL[k][tr * 4];
                float4 w1 = *(const float4*)&WL[k][128 + tr * 4];
                float av[8] = {a0.x, a0.y, a0.z, a0.w, a1.x, a1.y, a1.z, a1.w};
                float wv[8] = {w0.x, w0.y, w0.z, w0.w, w1.x, w1.y, w1.z, w1.w};
#pragma unroll
                for (int bi = 0; bi < 8; ++bi)
#pragma unroll
                    for (int m = 0; m < 8; ++m)
                        acc[bi][m] = fmaf(av[bi], wv[m], acc[bi][m]);
            }
        }
        // ---- write partials: Gpart[d*KS+kb][b][r] ----
        {
            float* gp = Gpart + (size_t)(d * KS + kb) * ((size_t)BATCH * G4);
#pragma unroll
            for (int bi = 0; bi < 8; ++bi) {
                float* row = gp + (size_t)(tb * 8 + bi) * G4 + r0;
                *(float4*)(row + tr * 4) =
                    make_float4(acc[bi][0], acc[bi][1], acc[bi][2], acc[bi][3]);
                *(float4*)(row + 128 + tr * 4) =
                    make_float4(acc[bi][4], acc[bi][5], acc[bi][6], acc[bi][7]);
            }
        }
        grid_barrier(barcnt, (++bar) * NBLK);

        // ================= phase 2: reduce + activations + state =================
        for (int e = gtid; e < E2; e += NBLK * NTHR) {
            int b = e / (2 * HID); int rr = e % (2 * HID); int dd = rr / HID; int j = rr % HID;
            const float* bs = dd ? bias1 : bias0;
            float gv[4];
#pragma unroll
            for (int gi = 0; gi < 4; ++gi) {
                int row = gi * HID + j;
                float s = bs[row];
#pragma unroll
                for (int q = 0; q < KS; ++q)
                    s += Gpart[(size_t)(dd * KS + q) * ((size_t)BATCH * G4) + (size_t)b * G4 + row];
                gv[gi] = s;
            }
            float ig = sigmoidf_(gv[0]);
            float fg = sigmoidf_(gv[1]);
            float gg = tanhf(gv[2]);
            float og = sigmoidf_(gv[3]);
            size_t ci = (size_t)(dd * BATCH + b) * HID + j;
            float cn = fg * cbuf[ci] + ig * gg;
            cbuf[ci] = cn;
            float hn = og * tanhf(cn);
            hT[(size_t)(dd * HID + j) * BATCH + b] = hn;
            int t_out = dd ? (SEQL - 1 - t) : t;
            out[((size_t)b * SEQL + t_out) * (2 * HID) + dd * HID + j] = hn;
            if (t == SEQL - 1) {
                out[HALLN + ci] = hn;            // h_n
                out[HALLN + E2 + ci] = cn;       // c_n
            }
        }
        grid_barrier(barcnt, (++bar) * NBLK);
    }
}

// ---------------- launcher ----------------
extern "C" void kernel_launch(void* const* d_in, const int* in_sizes, int n_in,
                              void* d_out, int out_size, void* d_ws, size_t ws_size,
                              hipStream_t stream) {
    const float* x     = (const float*)d_in[0];
    const float* wih0  = (const float*)d_in[1];
    const float* whh0  = (const float*)d_in[2];
    const float* bias0 = (const float*)d_in[3];
    const float* wih1  = (const float*)d_in[4];
    const float* whh1  = (const float*)d_in[5];
    const float* bias1 = (const float*)d_in[6];
    const float* h0    = (const float*)d_in[7];
    const float* c0    = (const float*)d_in[8];
    float* out = (float*)d_out;
    float* ws  = (float*)d_ws;

    // ws carve (floats)
    size_t off = 0;
    float* Gpart = ws + off; off += (size_t)2 * KS * BATCH * G4;   // 3,932,160
    float* hT    = ws + off; off += (size_t)2 * HID * BATCH;       //    98,304
    float* cbuf  = ws + off; off += (size_t)2 * BATCH * HID;       //    98,304
    unsigned* barcnt = (unsigned*)(ws + off); off += 64;           // 256 B, own line
    float* Wt = ws + off;
    size_t off_wt = off + (size_t)2 * KTOT * G4;                   // +7,864,320
    float* xT = ws + off_wt;
    size_t off_xt = off_wt + (size_t)SEQL * INDIM * BATCH;         // +16,777,216
    int use_wt = (ws_size >= off_wt * sizeof(float)) ? 1 : 0;
    int use_xt = (ws_size >= off_xt * sizeof(float)) ? 1 : 0;

    hipMemsetAsync(barcnt, 0, 256, stream);
    if (use_wt) k_pack_w<<<1920, 256, 0, stream>>>(wih0, whh0, wih1, whh1, Wt);
    if (use_xt) k_transpose_x<<<4096, 256, 0, stream>>>(x, xT);

    k_lstm_persist<<<NBLK, NTHR, 0, stream>>>(
        x, xT, use_xt, Wt, use_wt,
        wih0, whh0, wih1, whh1, bias0, bias1, h0, c0,
        out, Gpart, hT, cbuf, barcnt);
}